// Round 11
// baseline (81.258 us; speedup 1.0000x reference)
//
#include <hip/hip_runtime.h>
#include <math.h>

#define B    64
#define DQ   512
#define DO   256
#define NH   8
#define DH   32
#define HW   1024
#define NCH  16     // s-chunks per image
#define CHS  64     // s per chunk
#define CG   32     // channels per LDS tile
#define NT   (DO/CG) // 8 tiles

// ---------------------------------------------------------------- k1: qv = q @ w_q.T + b_q   (wave-per-output GEMV)
__global__ __launch_bounds__(256) void k1_qv(const float* __restrict__ q,
                                             const float* __restrict__ w_q,
                                             const float* __restrict__ b_q,
                                             float* __restrict__ qv) {
    int cg = blockIdx.x, b = blockIdx.y;
    int t = threadIdx.x;
    int wid = t >> 6, lane = t & 63;
    const float4* qrow = reinterpret_cast<const float4*>(q + (size_t)b*DQ);
    float4 q0 = qrow[lane*2], q1 = qrow[lane*2 + 1];
    #pragma unroll
    for (int r = 0; r < 4; ++r) {
        int c = cg*16 + wid*4 + r;
        const float4* wrow = reinterpret_cast<const float4*>(w_q + (size_t)c*DQ);
        float4 w0 = wrow[lane*2], w1 = wrow[lane*2 + 1];
        float acc = q0.x*w0.x + q0.y*w0.y + q0.z*w0.z + q0.w*w0.w
                  + q1.x*w1.x + q1.y*w1.y + q1.z*w1.z + q1.w*w1.w;
        #pragma unroll
        for (int k = 32; k > 0; k >>= 1) acc += __shfl_xor(acc, k);
        if (lane == 0) qv[b*DO + c] = acc + b_q[c];
    }
}

// ---------------------------------------------------------------- k2: fold qv into kc/kd weights
__global__ void k2_wqk(const float* __restrict__ qv,
                       const float* __restrict__ w_kc, const float* __restrict__ b_kc,
                       const float* __restrict__ w_kd, const float* __restrict__ b_kd,
                       const float* __restrict__ temp_c, const float* __restrict__ temp_d,
                       float* __restrict__ wqkc, float* __restrict__ wqkd,
                       float* __restrict__ qbc, float* __restrict__ qbd) {
    int bn = blockIdx.x;              // b*8 + n
    int n  = bn & 7;
    int t  = threadIdx.x;             // c
    __shared__ float qvs[DH];
    if (t < DH) qvs[t] = qv[(bn >> 3)*DO + n*DH + t];
    __syncthreads();
    float itc = 1.0f / temp_c[0];
    float itd = 1.0f / temp_d[0];
    float ac = 0.f, ad = 0.f;
    #pragma unroll
    for (int d = 0; d < DH; ++d) {
        float qd = qvs[d];
        ac += qd * w_kc[(n*DH + d)*DO + t];
        ad += qd * w_kd[(n*DH + d)*DO + t];
    }
    wqkc[bn*DO + t] = ac * itc;
    wqkd[bn*DO + t] = ad * itd;
    if (t == 0) {
        float sc = 0.f;
        for (int d = 0; d < DH; ++d) sc += qvs[d]*b_kc[n*DH + d];
        qbc[bn] = sc * itc;
    }
    if (t == 1) {
        float sd = 0.f;
        for (int d = 0; d < DH; ++d) sd += qvs[d]*b_kd[n*DH + d];
        qbd[bn] = sd * itd;
    }
}

// ---------------------------------------------------------------- k3i: LDS-tile-staged logits + gate + wave-local softmax + pool
// grid (NCH=16, B) = 1024 blocks (4/CU), block 512 (8 waves) -> 32 waves/CU.
// Phase 1: double-buffered 32x64 v tiles; 1 coalesced float4 global load per
// thread per tile (issue-early / LDS-store-late); wave n = head n; lane = s.
__global__ __launch_bounds__(512, 8)
void k3i(const float* __restrict__ v,
         const float* __restrict__ wqkc, const float* __restrict__ wqkd,
         const float* __restrict__ qbc,  const float* __restrict__ qbd,
         float* __restrict__ gate, float* __restrict__ pvp, float* __restrict__ mz) {
    __shared__ float buf[2][CG][CHS];    // 2 x 8 KB v tiles
    __shared__ float e_lds[NH][CHS];     // 2 KB
    int ch = blockIdx.x, b = blockIdx.y;
    int t  = threadIdx.x;
    int s0 = ch*CHS;
    int bn0 = b*NH;
    int lane = t & 63;
    int w = __builtin_amdgcn_readfirstlane(t >> 6);   // wave id = head

    // staging map: thread -> (row = t>>4 in [0,32), col4 = t&15)
    int srow = t >> 4, sc4 = (t & 15)*4;
    const float* vb = v + (size_t)b*DO*HW + s0;

    // ---- prefill tile 0
    {
        float4 st = *reinterpret_cast<const float4*>(vb + (size_t)srow*HW + sc4);
        *reinterpret_cast<float4*>(&buf[0][srow][sc4]) = st;
    }
    __syncthreads();

    // ---- phase 1: logits over 8 tiles, dbuf
    float lc = qbc[bn0 + w];
    float ld = qbd[bn0 + w];
    const float* wcn = wqkc + (size_t)(bn0 + w)*DO;
    const float* wdn = wqkd + (size_t)(bn0 + w)*DO;
    #pragma unroll
    for (int g = 0; g < NT; ++g) {
        int cur = g & 1;
        float4 nx;
        if (g < NT-1)   // issue next tile's load early
            nx = *reinterpret_cast<const float4*>(vb + (size_t)((g+1)*CG + srow)*HW + sc4);
        int cbase = g*CG;
        #pragma unroll
        for (int cc = 0; cc < CG; ++cc) {
            float vv = buf[cur][cc][lane];
            lc = fmaf(wcn[cbase + cc], vv, lc);
            ld = fmaf(wdn[cbase + cc], vv, ld);
        }
        if (g < NT-1)   // write-late: store after compute
            *reinterpret_cast<float4*>(&buf[cur ^ 1][srow][sc4]) = nx;
        __syncthreads();
    }

    // ---- phase 2: wave-local gate + softmax stats (head w, 64 s in-wave)
    {
        gate[(size_t)(bn0 + w)*HW + s0 + lane] = 1.0f/(1.0f + __expf(-ld));
        float m = lc;
        #pragma unroll
        for (int k = 32; k > 0; k >>= 1) m = fmaxf(m, __shfl_xor(m, k));
        float e = __expf(lc - m);
        e_lds[w][lane] = e;
        float z = e;
        #pragma unroll
        for (int k = 32; k > 0; k >>= 1) z += __shfl_xor(z, k);
        if (lane == 0) {
            float* mzp = mz + ((size_t)(b*NCH + ch)*NH + w)*2;
            mzp[0] = m; mzp[1] = z;
        }
    }
    __syncthreads();

    // ---- phase 3: partial pool, transposed map: thread -> (c, 4 heads), s serial (L2-hot)
    {
        int ng = t >> 8;                 // 0 or 1
        int c  = t & 255;
        const float* vrow = v + ((size_t)(b*DO + c))*HW + s0;
        float a0 = 0.f, a1 = 0.f, a2 = 0.f, a3 = 0.f;
        #pragma unroll
        for (int j = 0; j < CHS/4; ++j) {
            float4 v4 = *reinterpret_cast<const float4*>(vrow + j*4);
            float4 e0 = *reinterpret_cast<const float4*>(&e_lds[ng*4+0][j*4]);
            float4 e1 = *reinterpret_cast<const float4*>(&e_lds[ng*4+1][j*4]);
            float4 e2 = *reinterpret_cast<const float4*>(&e_lds[ng*4+2][j*4]);
            float4 e3 = *reinterpret_cast<const float4*>(&e_lds[ng*4+3][j*4]);
            a0 += v4.x*e0.x + v4.y*e0.y + v4.z*e0.z + v4.w*e0.w;
            a1 += v4.x*e1.x + v4.y*e1.y + v4.z*e1.z + v4.w*e1.w;
            a2 += v4.x*e2.x + v4.y*e2.y + v4.z*e2.z + v4.w*e2.w;
            a3 += v4.x*e3.x + v4.y*e3.y + v4.z*e3.z + v4.w*e3.w;
        }
        size_t pb = ((size_t)(b*NCH + ch)*NH + ng*4)*DO + c;
        pvp[pb]        = a0;
        pvp[pb + DO]   = a1;
        pvp[pb + 2*DO] = a2;
        pvp[pb + 3*DO] = a3;
    }
}

// ---------------------------------------------------------------- k4c: softmax-scale combine of 16 chunks + GEMV
__global__ void k4c(const float* __restrict__ pvp, const float* __restrict__ mz,
                    const float* __restrict__ w_v, const float* __restrict__ b_v,
                    float* __restrict__ attn) {
    __shared__ float scale[NCH][NH];
    __shared__ float pv_lds[NH*DO];
    int b = blockIdx.x, t = threadIdx.x;
    if (t < NH) {
        int n = t;
        float M = -1e30f;
        for (int ch = 0; ch < NCH; ++ch)
            M = fmaxf(M, mz[((size_t)(b*NCH+ch)*NH+n)*2]);
        float Z = 0.f;
        for (int ch = 0; ch < NCH; ++ch) {
            float sc = __expf(mz[((size_t)(b*NCH+ch)*NH+n)*2] - M);
            Z += sc * mz[((size_t)(b*NCH+ch)*NH+n)*2 + 1];
            scale[ch][n] = sc;
        }
        float inv = 1.0f/Z;
        for (int ch = 0; ch < NCH; ++ch) scale[ch][n] *= inv;
    }
    __syncthreads();
    #pragma unroll
    for (int r = 0; r < 2; ++r) {
        int i4 = t + r*256;              // float4 index, head = i4/64
        int n  = i4 >> 6;
        float4 s = make_float4(0.f, 0.f, 0.f, 0.f);
        #pragma unroll
        for (int ch = 0; ch < NCH; ++ch) {
            float sc = scale[ch][n];
            float4 p = reinterpret_cast<const float4*>(pvp + (size_t)(b*NCH + ch)*NH*DO)[i4];
            s.x = fmaf(sc, p.x, s.x); s.y = fmaf(sc, p.y, s.y);
            s.z = fmaf(sc, p.z, s.z); s.w = fmaf(sc, p.w, s.w);
        }
        *reinterpret_cast<float4*>(&pv_lds[i4*4]) = s;
    }
    __syncthreads();
    int n = t >> 5;
    float acc = b_v[t];
    const float4* w4 = reinterpret_cast<const float4*>(w_v + t*DO);
    #pragma unroll 4
    for (int c4 = 0; c4 < DO/4; ++c4) {
        float4 wv = w4[c4];
        int c = c4*4;
        acc += pv_lds[n*DO+c]*wv.x + pv_lds[n*DO+c+1]*wv.y + pv_lds[n*DO+c+2]*wv.z + pv_lds[n*DO+c+3]*wv.w;
    }
    attn[b*DO + t] = acc;
}

// ---------------------------------------------------------------- k5: out = leaky(bn(gate[s^T]*attn + v))
__global__ void k5_out(const float* __restrict__ v, const float* __restrict__ gate,
                       const float* __restrict__ attn,
                       const float* __restrict__ bn_g, const float* __restrict__ bn_b,
                       const float* __restrict__ bn_m, const float* __restrict__ bn_v,
                       float* __restrict__ out) {
    int c = blockIdx.x, b = blockIdx.y;
    int n = c >> 5, d = c & 31;
    int t = threadIdx.x;
    __shared__ float g[32*33];             // stride 33 kills transpose bank conflicts
    float4 gv = reinterpret_cast<const float4*>(gate + (b*NH + n)*HW)[t];
    int s0 = t*4;
    int ga = s0 >> 5, gb = s0 & 31;
    g[ga*33 + gb + 0] = gv.x;
    g[ga*33 + gb + 1] = gv.y;
    g[ga*33 + gb + 2] = gv.z;
    g[ga*33 + gb + 3] = gv.w;
    __syncthreads();
    float av   = attn[(b*NH + n)*DH + d];
    float inv  = bn_g[c] / sqrtf(bn_v[c] + 1e-5f);
    float mean = bn_m[c], beta = bn_b[c];
    size_t base = ((size_t)(b*DO + c))*HW;
    float4 r4 = reinterpret_cast<const float4*>(v + base)[t];
    int l = 4*t;
    int i_ = l >> 5, j_ = l & 31;          // gate index s = j*32 + i
    float x0 = g[(j_+0)*33 + i_]*av + r4.x;
    float x1 = g[(j_+1)*33 + i_]*av + r4.y;
    float x2 = g[(j_+2)*33 + i_]*av + r4.z;
    float x3 = g[(j_+3)*33 + i_]*av + r4.w;
    float y0 = (x0 - mean)*inv + beta; y0 = y0 >= 0.f ? y0 : 0.1f*y0;
    float y1 = (x1 - mean)*inv + beta; y1 = y1 >= 0.f ? y1 : 0.1f*y1;
    float y2 = (x2 - mean)*inv + beta; y2 = y2 >= 0.f ? y2 : 0.1f*y2;
    float y3 = (x3 - mean)*inv + beta; y3 = y3 >= 0.f ? y3 : 0.1f*y3;
    reinterpret_cast<float4*>(out + base)[t] = make_float4(y0, y1, y2, y3);
}

// ----------------------------------------------------------------
extern "C" void kernel_launch(void* const* d_in, const int* in_sizes, int n_in,
                              void* d_out, int out_size, void* d_ws, size_t ws_size,
                              hipStream_t stream) {
    const float* q      = (const float*)d_in[0];
    const float* v      = (const float*)d_in[1];
    const float* w_q    = (const float*)d_in[2];
    const float* b_q    = (const float*)d_in[3];
    const float* w_kc   = (const float*)d_in[4];
    const float* b_kc   = (const float*)d_in[5];
    const float* w_kd   = (const float*)d_in[6];
    const float* b_kd   = (const float*)d_in[7];
    const float* w_v    = (const float*)d_in[8];
    const float* b_v    = (const float*)d_in[9];
    const float* temp_c = (const float*)d_in[10];
    const float* temp_d = (const float*)d_in[11];
    const float* bn_g   = (const float*)d_in[12];
    const float* bn_b   = (const float*)d_in[13];
    const float* bn_m   = (const float*)d_in[14];
    const float* bn_v   = (const float*)d_in[15];
    float* out = (float*)d_out;

    float* ws   = (float*)d_ws;
    float* qv   = ws;                     // B*DO         = 16384
    float* wqkc = qv   + B*DO;            // B*NH*DO      = 131072
    float* wqkd = wqkc + B*NH*DO;         // 131072
    float* qbc  = wqkd + B*NH*DO;         // 512
    float* qbd  = qbc  + B*NH;            // 512
    float* gate = qbd  + B*NH;            // B*NH*HW      = 524288
    float* mz   = gate + B*NH*HW;         // B*NCH*NH*2   = 16384
    float* pvp  = mz   + B*NCH*NH*2;      // B*NCH*NH*DO  = 2097152
    float* attn = pvp  + B*NCH*NH*DO;     // B*DO         = 16384

    k1_qv <<<dim3(16, B),    256, 0, stream>>>(q, w_q, b_q, qv);
    k2_wqk<<<B*NH,           256, 0, stream>>>(qv, w_kc, b_kc, w_kd, b_kd, temp_c, temp_d,
                                               wqkc, wqkd, qbc, qbd);
    k3i   <<<dim3(NCH, B),   512, 0, stream>>>(v, wqkc, wqkd, qbc, qbd, gate, pvp, mz);
    k4c   <<<B,              256, 0, stream>>>(pvp, mz, w_v, b_v, attn);
    k5_out<<<dim3(DO, B),    256, 0, stream>>>(v, gate, attn, bn_g, bn_b, bn_m, bn_v, out);
}

// Round 12
// 80.297 us; speedup vs baseline: 1.0120x; 1.0120x over previous
//
#include <hip/hip_runtime.h>
#include <math.h>

#define B    64
#define DQ   512
#define DO   256
#define NH   8
#define DH   32
#define HW   1024
#define NCH  16     // s-chunks per image
#define CHS  64     // s per chunk

// ---------------------------------------------------------------- k1: qv = q @ w_q.T + b_q   (wave-per-output GEMV)
__global__ __launch_bounds__(256) void k1_qv(const float* __restrict__ q,
                                             const float* __restrict__ w_q,
                                             const float* __restrict__ b_q,
                                             float* __restrict__ qv) {
    int cg = blockIdx.x, b = blockIdx.y;
    int t = threadIdx.x;
    int wid = t >> 6, lane = t & 63;
    const float4* qrow = reinterpret_cast<const float4*>(q + (size_t)b*DQ);
    float4 q0 = qrow[lane*2], q1 = qrow[lane*2 + 1];
    #pragma unroll
    for (int r = 0; r < 4; ++r) {
        int c = cg*16 + wid*4 + r;
        const float4* wrow = reinterpret_cast<const float4*>(w_q + (size_t)c*DQ);
        float4 w0 = wrow[lane*2], w1 = wrow[lane*2 + 1];
        float acc = q0.x*w0.x + q0.y*w0.y + q0.z*w0.z + q0.w*w0.w
                  + q1.x*w1.x + q1.y*w1.y + q1.z*w1.z + q1.w*w1.w;
        #pragma unroll
        for (int k = 32; k > 0; k >>= 1) acc += __shfl_xor(acc, k);
        if (lane == 0) qv[b*DO + c] = acc + b_q[c];
    }
}

// ---------------------------------------------------------------- k2: fold qv into kc/kd weights
__global__ void k2_wqk(const float* __restrict__ qv,
                       const float* __restrict__ w_kc, const float* __restrict__ b_kc,
                       const float* __restrict__ w_kd, const float* __restrict__ b_kd,
                       const float* __restrict__ temp_c, const float* __restrict__ temp_d,
                       float* __restrict__ wqkc, float* __restrict__ wqkd,
                       float* __restrict__ qbc, float* __restrict__ qbd) {
    int bn = blockIdx.x;              // b*8 + n
    int n  = bn & 7;
    int t  = threadIdx.x;             // c
    __shared__ float qvs[DH];
    if (t < DH) qvs[t] = qv[(bn >> 3)*DO + n*DH + t];
    __syncthreads();
    float itc = 1.0f / temp_c[0];
    float itd = 1.0f / temp_d[0];
    float ac = 0.f, ad = 0.f;
    #pragma unroll
    for (int d = 0; d < DH; ++d) {
        float qd = qvs[d];
        ac += qd * w_kc[(n*DH + d)*DO + t];
        ad += qd * w_kd[(n*DH + d)*DO + t];
    }
    wqkc[bn*DO + t] = ac * itc;
    wqkd[bn*DO + t] = ad * itd;
    if (t == 0) {
        float sc = 0.f;
        for (int d = 0; d < DH; ++d) sc += qvs[d]*b_kc[n*DH + d];
        qbc[bn] = sc * itc;
    }
    if (t == 1) {
        float sd = 0.f;
        for (int d = 0; d < DH; ++d) sd += qvs[d]*b_kd[n*DH + d];
        qbd[bn] = sd * itd;
    }
}

// ---------------------------------------------------------------- k3j: full-slice LDS staging (swizzled) + logits + softmax + pool
// grid (NCH=16, B) = 1024 blocks (2/CU via 66KB LDS), block 512 (8 waves).
// Swizzle: 16B group s4 stored at s4 ^ (c&15)  -> conflict-free for both
// per-lane-s reads (phase 1) and per-c float4 reads (phase 3).
__global__ __launch_bounds__(512, 4)
void k3j(const float* __restrict__ v,
         const float* __restrict__ wqkc, const float* __restrict__ wqkd,
         const float* __restrict__ qbc,  const float* __restrict__ qbd,
         float* __restrict__ gate, float* __restrict__ pvp, float* __restrict__ mz) {
    __shared__ float vbuf[DO][CHS];      // 64 KB swizzled v slice
    __shared__ float e_lds[NH][CHS];     // 2 KB
    int ch = blockIdx.x, b = blockIdx.y;
    int t  = threadIdx.x;
    int s0 = ch*CHS;
    int bn0 = b*NH;
    int lane = t & 63;
    int w = __builtin_amdgcn_readfirstlane(t >> 6);   // wave id = head

    // ---- stage: 8 coalesced float4 loads per thread, all in flight, swizzled store
    {
        int s4 = t & 15, srow = t >> 4;               // srow in [0,32)
        const float* vb = v + (size_t)b*DO*HW + s0;
        float4 r0 = *reinterpret_cast<const float4*>(vb + (size_t)(0*32+srow)*HW + s4*4);
        float4 r1 = *reinterpret_cast<const float4*>(vb + (size_t)(1*32+srow)*HW + s4*4);
        float4 r2 = *reinterpret_cast<const float4*>(vb + (size_t)(2*32+srow)*HW + s4*4);
        float4 r3 = *reinterpret_cast<const float4*>(vb + (size_t)(3*32+srow)*HW + s4*4);
        float4 r4 = *reinterpret_cast<const float4*>(vb + (size_t)(4*32+srow)*HW + s4*4);
        float4 r5 = *reinterpret_cast<const float4*>(vb + (size_t)(5*32+srow)*HW + s4*4);
        float4 r6 = *reinterpret_cast<const float4*>(vb + (size_t)(6*32+srow)*HW + s4*4);
        float4 r7 = *reinterpret_cast<const float4*>(vb + (size_t)(7*32+srow)*HW + s4*4);
        int idx4 = (s4 ^ (srow & 15)) * 4;            // c&15 == srow&15 for all tiles
        *reinterpret_cast<float4*>(&vbuf[0*32+srow][idx4]) = r0;
        *reinterpret_cast<float4*>(&vbuf[1*32+srow][idx4]) = r1;
        *reinterpret_cast<float4*>(&vbuf[2*32+srow][idx4]) = r2;
        *reinterpret_cast<float4*>(&vbuf[3*32+srow][idx4]) = r3;
        *reinterpret_cast<float4*>(&vbuf[4*32+srow][idx4]) = r4;
        *reinterpret_cast<float4*>(&vbuf[5*32+srow][idx4]) = r5;
        *reinterpret_cast<float4*>(&vbuf[6*32+srow][idx4]) = r6;
        *reinterpret_cast<float4*>(&vbuf[7*32+srow][idx4]) = r7;
    }
    __syncthreads();

    // ---- phase 1: wave w computes head-w logits for its 64 s (lane = s)
    float lcA = 0.f, lcB = 0.f, ldA = 0.f, ldB = 0.f;
    {
        const float* wcn = wqkc + (size_t)(bn0 + w)*DO;
        const float* wdn = wqkd + (size_t)(bn0 + w)*DO;
        int sq = lane >> 2, sk = lane & 3;
        #pragma unroll 8
        for (int c = 0; c < DO; c += 2) {
            float v0 = vbuf[c    ][((sq ^ (c     & 15)) << 2) | sk];
            float v1 = vbuf[c + 1][((sq ^ ((c+1) & 15)) << 2) | sk];
            lcA = fmaf(wcn[c],   v0, lcA);
            ldA = fmaf(wdn[c],   v0, ldA);
            lcB = fmaf(wcn[c+1], v1, lcB);
            ldB = fmaf(wdn[c+1], v1, ldB);
        }
    }

    // ---- phase 2: wave-local gate + softmax stats
    {
        float lc = lcA + lcB + qbc[bn0 + w];
        float ld = ldA + ldB + qbd[bn0 + w];
        gate[(size_t)(bn0 + w)*HW + s0 + lane] = 1.0f/(1.0f + __expf(-ld));
        float m = lc;
        #pragma unroll
        for (int k = 32; k > 0; k >>= 1) m = fmaxf(m, __shfl_xor(m, k));
        float e = __expf(lc - m);
        e_lds[w][lane] = e;
        float z = e;
        #pragma unroll
        for (int k = 32; k > 0; k >>= 1) z += __shfl_xor(z, k);
        if (lane == 0) {
            float* mzp = mz + ((size_t)(b*NCH + ch)*NH + w)*2;
            mzp[0] = m; mzp[1] = z;
        }
    }
    __syncthreads();

    // ---- phase 3: pool from LDS; thread pair per channel; conflict-free via swizzle
    {
        int c = t >> 1, sh = t & 1;
        int cx = (c & 15);
        float4 vr[8];
        #pragma unroll
        for (int j = 0; j < 8; ++j) {
            int s4r = sh*8 + j;
            vr[j] = *reinterpret_cast<const float4*>(&vbuf[c][(s4r ^ cx) * 4]);
        }
        float acc[NH];
        #pragma unroll
        for (int n = 0; n < NH; ++n) {
            float a = 0.f;
            #pragma unroll
            for (int j = 0; j < 8; ++j) {
                int s4r = sh*8 + j;
                float4 e4 = *reinterpret_cast<const float4*>(&e_lds[n][s4r*4]);
                a += vr[j].x*e4.x + vr[j].y*e4.y + vr[j].z*e4.z + vr[j].w*e4.w;
            }
            a += __shfl_xor(a, 1);
            acc[n] = a;
        }
        if (sh == 0) {
            size_t pb = ((size_t)(b*NCH + ch)*NH)*DO + c;
            #pragma unroll
            for (int n = 0; n < NH; ++n) pvp[pb + n*DO] = acc[n];
        }
    }
}

// ---------------------------------------------------------------- k4c: softmax-scale combine of 16 chunks + GEMV
__global__ void k4c(const float* __restrict__ pvp, const float* __restrict__ mz,
                    const float* __restrict__ w_v, const float* __restrict__ b_v,
                    float* __restrict__ attn) {
    __shared__ float scale[NCH][NH];
    __shared__ float pv_lds[NH*DO];
    int b = blockIdx.x, t = threadIdx.x;
    if (t < NH) {
        int n = t;
        float M = -1e30f;
        for (int ch = 0; ch < NCH; ++ch)
            M = fmaxf(M, mz[((size_t)(b*NCH+ch)*NH+n)*2]);
        float Z = 0.f;
        for (int ch = 0; ch < NCH; ++ch) {
            float sc = __expf(mz[((size_t)(b*NCH+ch)*NH+n)*2] - M);
            Z += sc * mz[((size_t)(b*NCH+ch)*NH+n)*2 + 1];
            scale[ch][n] = sc;
        }
        float inv = 1.0f/Z;
        for (int ch = 0; ch < NCH; ++ch) scale[ch][n] *= inv;
    }
    __syncthreads();
    #pragma unroll
    for (int r = 0; r < 2; ++r) {
        int i4 = t + r*256;              // float4 index, head = i4/64
        int n  = i4 >> 6;
        float4 s = make_float4(0.f, 0.f, 0.f, 0.f);
        #pragma unroll 4
        for (int ch = 0; ch < NCH; ++ch) {
            float sc = scale[ch][n];
            float4 p = reinterpret_cast<const float4*>(pvp + (size_t)(b*NCH + ch)*NH*DO)[i4];
            s.x = fmaf(sc, p.x, s.x); s.y = fmaf(sc, p.y, s.y);
            s.z = fmaf(sc, p.z, s.z); s.w = fmaf(sc, p.w, s.w);
        }
        *reinterpret_cast<float4*>(&pv_lds[i4*4]) = s;
    }
    __syncthreads();
    int n = t >> 5;
    float acc = b_v[t];
    const float4* w4 = reinterpret_cast<const float4*>(w_v + t*DO);
    #pragma unroll 4
    for (int c4 = 0; c4 < DO/4; ++c4) {
        float4 wv = w4[c4];
        int c = c4*4;
        acc += pv_lds[n*DO+c]*wv.x + pv_lds[n*DO+c+1]*wv.y + pv_lds[n*DO+c+2]*wv.z + pv_lds[n*DO+c+3]*wv.w;
    }
    attn[b*DO + t] = acc;
}

// ---------------------------------------------------------------- k5: out = leaky(bn(gate[s^T]*attn + v))
__global__ void k5_out(const float* __restrict__ v, const float* __restrict__ gate,
                       const float* __restrict__ attn,
                       const float* __restrict__ bn_g, const float* __restrict__ bn_b,
                       const float* __restrict__ bn_m, const float* __restrict__ bn_v,
                       float* __restrict__ out) {
    int c = blockIdx.x, b = blockIdx.y;
    int n = c >> 5, d = c & 31;
    int t = threadIdx.x;
    __shared__ float g[32*33];             // stride 33 kills transpose bank conflicts
    float4 gv = reinterpret_cast<const float4*>(gate + (b*NH + n)*HW)[t];
    int s0 = t*4;
    int ga = s0 >> 5, gb = s0 & 31;
    g[ga*33 + gb + 0] = gv.x;
    g[ga*33 + gb + 1] = gv.y;
    g[ga*33 + gb + 2] = gv.z;
    g[ga*33 + gb + 3] = gv.w;
    __syncthreads();
    float av   = attn[(b*NH + n)*DH + d];
    float inv  = bn_g[c] / sqrtf(bn_v[c] + 1e-5f);
    float mean = bn_m[c], beta = bn_b[c];
    size_t base = ((size_t)(b*DO + c))*HW;
    float4 r4 = reinterpret_cast<const float4*>(v + base)[t];
    int l = 4*t;
    int i_ = l >> 5, j_ = l & 31;          // gate index s = j*32 + i
    float x0 = g[(j_+0)*33 + i_]*av + r4.x;
    float x1 = g[(j_+1)*33 + i_]*av + r4.y;
    float x2 = g[(j_+2)*33 + i_]*av + r4.z;
    float x3 = g[(j_+3)*33 + i_]*av + r4.w;
    float y0 = (x0 - mean)*inv + beta; y0 = y0 >= 0.f ? y0 : 0.1f*y0;
    float y1 = (x1 - mean)*inv + beta; y1 = y1 >= 0.f ? y1 : 0.1f*y1;
    float y2 = (x2 - mean)*inv + beta; y2 = y2 >= 0.f ? y2 : 0.1f*y2;
    float y3 = (x3 - mean)*inv + beta; y3 = y3 >= 0.f ? y3 : 0.1f*y3;
    reinterpret_cast<float4*>(out + base)[t] = make_float4(y0, y1, y2, y3);
}

// ----------------------------------------------------------------
extern "C" void kernel_launch(void* const* d_in, const int* in_sizes, int n_in,
                              void* d_out, int out_size, void* d_ws, size_t ws_size,
                              hipStream_t stream) {
    const float* q      = (const float*)d_in[0];
    const float* v      = (const float*)d_in[1];
    const float* w_q    = (const float*)d_in[2];
    const float* b_q    = (const float*)d_in[3];
    const float* w_kc   = (const float*)d_in[4];
    const float* b_kc   = (const float*)d_in[5];
    const float* w_kd   = (const float*)d_in[6];
    const float* b_kd   = (const float*)d_in[7];
    const float* w_v    = (const float*)d_in[8];
    const float* b_v    = (const float*)d_in[9];
    const float* temp_c = (const float*)d_in[10];
    const float* temp_d = (const float*)d_in[11];
    const float* bn_g   = (const float*)d_in[12];
    const float* bn_b   = (const float*)d_in[13];
    const float* bn_m   = (const float*)d_in[14];
    const float* bn_v   = (const float*)d_in[15];
    float* out = (float*)d_out;

    float* ws   = (float*)d_ws;
    float* qv   = ws;                     // B*DO         = 16384
    float* wqkc = qv   + B*DO;            // B*NH*DO      = 131072
    float* wqkd = wqkc + B*NH*DO;         // 131072
    float* qbc  = wqkd + B*NH*DO;         // 512
    float* qbd  = qbc  + B*NH;            // 512
    float* gate = qbd  + B*NH;            // B*NH*HW      = 524288
    float* mz   = gate + B*NH*HW;         // B*NCH*NH*2   = 16384
    float* pvp  = mz   + B*NCH*NH*2;      // B*NCH*NH*DO  = 2097152
    float* attn = pvp  + B*NCH*NH*DO;     // B*DO         = 16384

    k1_qv <<<dim3(16, B),    256, 0, stream>>>(q, w_q, b_q, qv);
    k2_wqk<<<B*NH,           256, 0, stream>>>(qv, w_kc, b_kc, w_kd, b_kd, temp_c, temp_d,
                                               wqkc, wqkd, qbc, qbd);
    k3j   <<<dim3(NCH, B),   512, 0, stream>>>(v, wqkc, wqkd, qbc, qbd, gate, pvp, mz);
    k4c   <<<B,              256, 0, stream>>>(pvp, mz, w_v, b_v, attn);
    k5_out<<<dim3(DO, B),    256, 0, stream>>>(v, gate, attn, bn_g, bn_b, bn_m, bn_v, out);
}